// Round 18
// baseline (40.865 us; speedup 1.0000x reference)
//
#include <hip/hip_runtime.h>
#include <hip/hip_fp16.h>

#define HH 512
#define WW 512
#define NPIX (HH*WW)
#define NBANDS 32
#define BAND (HH/NBANDS)     // 16 output rows per wave
#define PINF2 0x7C007C00u    // packed f16 +inf
#define NINF2 0xFC00FC00u    // packed f16 -inf

// ---- packed f16 ops as VOP3P inline asm (proven rounds 8-17) ----
typedef unsigned uh2;
__device__ __forceinline__ uh2 pmin(uh2 a, uh2 b){ uh2 r; asm("v_pk_min_f16 %0, %1, %2" : "=v"(r) : "v"(a), "v"(b)); return r; }
__device__ __forceinline__ uh2 pmax(uh2 a, uh2 b){ uh2 r; asm("v_pk_max_f16 %0, %1, %2" : "=v"(r) : "v"(a), "v"(b)); return r; }
__device__ __forceinline__ uh2 padd(uh2 a, uh2 b){ uh2 r; asm("v_pk_add_f16 %0, %1, %2" : "=v"(r) : "v"(a), "v"(b)); return r; }
__device__ __forceinline__ uh2 psub(uh2 a, uh2 b){ uh2 r; asm("v_pk_add_f16 %0, %1, %2 neg_lo:[0,1] neg_hi:[0,1]" : "=v"(r) : "v"(a), "v"(b)); return r; }
__device__ __forceinline__ uh2 pnfma(uh2 s, uh2 d){ uh2 r; asm("v_pk_fma_f16 %0, %1, %2, %2 neg_lo:[1,0,0] neg_hi:[1,0,0]" : "=v"(r) : "v"(s), "v"(d)); return r; }
__device__ __forceinline__ uh2 pmin3(uh2 a, uh2 b, uh2 c){ return pmin(pmin(a,b),c); }
__device__ __forceinline__ uh2 pmax3(uh2 a, uh2 b, uh2 c){ return pmax(pmax(a,b),c); }
__device__ __forceinline__ uh2 alignh(uh2 lo, uh2 hi){
    uh2 r; asm("v_alignbit_b32 %0, %1, %2, 16" : "=v"(r) : "v"(hi), "v"(lo)); return r;
}
__device__ __forceinline__ uh2 pkrtz(float x, float y){
    uh2 r; asm("v_cvt_pkrtz_f16_f32 %0, %1, %2" : "=v"(r) : "v"(x), "v"(y)); return r;
}
__device__ __forceinline__ float lo_f(uh2 v){ union { uh2 u; __half2 h; } c; c.u = v; return __low2float(c.h); }
__device__ __forceinline__ float hi_f(uh2 v){ union { uh2 u; __half2 h; } c; c.u = v; return __high2float(c.h); }

// ---- DPP full-wave lane shifts ----
__device__ __forceinline__ uh2 dshr1(uh2 v, unsigned old){   // lane i <- lane i-1
    return (uh2)__builtin_amdgcn_update_dpp((int)old, (int)v, 0x138, 0xF, 0xF, false);
}
__device__ __forceinline__ uh2 dshl1(uh2 v, unsigned old){   // lane i <- lane i+1
    return (uh2)__builtin_amdgcn_update_dpp((int)old, (int)v, 0x130, 0xF, 0xF, false);
}

struct R4 { uh2 a, b, c, d; };
__device__ __forceinline__ R4 r4splat(uh2 v){ R4 r; r.a=v; r.b=v; r.c=v; r.d=v; return r; }
__device__ __forceinline__ void ldraw(const float* p, float4& u, float4& v){
    u = *(const float4*)p; v = *(const float4*)(p + 4);
}
__device__ __forceinline__ R4 cvtrow(const float4& u, const float4& v){
    R4 r; r.a = pkrtz(u.x,u.y); r.b = pkrtz(u.z,u.w); r.c = pkrtz(v.x,v.y); r.d = pkrtz(v.z,v.w);
    return r;
}
__device__ __forceinline__ R4 vmin3(const R4& x, const R4& y, const R4& z){
    R4 r; r.a=pmin3(x.a,y.a,z.a); r.b=pmin3(x.b,y.b,z.b); r.c=pmin3(x.c,y.c,z.c); r.d=pmin3(x.d,y.d,z.d); return r;
}
__device__ __forceinline__ R4 vmax3(const R4& x, const R4& y, const R4& z){
    R4 r; r.a=pmax3(x.a,y.a,z.a); r.b=pmax3(x.b,y.b,z.b); r.c=pmax3(x.c,y.c,z.c); r.d=pmax3(x.d,y.d,z.d); return r;
}
__device__ __forceinline__ R4 rmin(const R4& x, const R4& y){
    R4 r; r.a=pmin(x.a,y.a); r.b=pmin(x.b,y.b); r.c=pmin(x.c,y.c); r.d=pmin(x.d,y.d); return r;
}
__device__ __forceinline__ R4 relusub(const R4& p, const R4& d){
    R4 r; r.a=pmax(psub(p.a,d.a),0u); r.b=pmax(psub(p.b,d.b),0u);
          r.c=pmax(psub(p.c,d.c),0u); r.d=pmax(psub(p.d,d.d),0u); return r;
}
__device__ __forceinline__ void skupd2(R4& s, const R4& d){
    s.a = padd(s.a, pnfma(s.a,d.a));
    s.b = padd(s.b, pnfma(s.b,d.b));
    s.c = padd(s.c, pnfma(s.c,d.c));
    s.d = padd(s.d, pnfma(s.d,d.d));
}
__device__ __forceinline__ R4 hminLR(const R4& x){
    uh2 L  = dshr1(x.d, PINF2);
    uh2 Rv = dshl1(x.a, PINF2);
    uh2 s0=alignh(L,x.a), s1=alignh(x.a,x.b), s2=alignh(x.b,x.c), s3=alignh(x.c,x.d), s4=alignh(x.d,Rv);
    R4 m; m.a=pmin(s0,s1); m.b=pmin(s1,s2); m.c=pmin(s2,s3); m.d=pmin(s3,s4); return m;
}
__device__ __forceinline__ R4 hmax3w(const R4& x){
    uh2 L  = dshr1(x.d, NINF2);
    uh2 Rv = dshl1(x.a, NINF2);
    uh2 s0=alignh(L,x.a), s1=alignh(x.a,x.b), s2=alignh(x.b,x.c), s3=alignh(x.c,x.d), s4=alignh(x.d,Rv);
    R4 m; m.a=pmax3(s0,x.a,s1); m.b=pmax3(s1,x.b,s2); m.c=pmax3(s2,x.c,s3); m.d=pmax3(s3,x.d,s4); return m;
}
__device__ __forceinline__ void finred(const R4& skF, const float4& o1, const float4& o2,
                                       float& sa, float& sb){
    float c0=lo_f(skF.a), c1=hi_f(skF.a), c2=lo_f(skF.b), c3=hi_f(skF.b);
    float c4=lo_f(skF.c), c5=hi_f(skF.c), c6=lo_f(skF.d), c7=hi_f(skF.d);
    sa += ((c0+c1)+(c2+c3)) + ((c4+c5)+(c6+c7));
    sb += ((c0*o1.x + c1*o1.y) + (c2*o1.z + c3*o1.w))
        + ((c4*o2.x + c5*o2.y) + (c6*o2.z + c7*o2.w));
}

// ---------- FAST step: interior bands; no oth/fin work (batched) ----------
__device__ __forceinline__ void step_fast(
    int g,
    const float* __restrict__ img,
    R4& i2, R4& i1, float4& pr1, float4& pr2,
    R4& e1p, R4& e1pp, R4& e2p, R4& e2pp, R4& e3p, R4& e3pp, R4& e4p, R4& e4pp,
    R4& skB, R4& skD1, R4& skD2, R4& skF, R4& pend)
{
    R4 i0 = cvtrow(pr1, pr2);                          // waits img issued 4 steps ago
    ldraw(img + (size_t)(g + 4) * WW, pr1, pr2);       // 4-deep prefetch (rows always valid)

    R4 e1n = rmin(vmin3(i2, i1, i0), hminLR(i1));
    R4 d1  = hmax3w(vmax3(e1pp, e1p, e1n));            // dilate(e1) @ g-2
    skB = relusub(i2, d1);

    R4 e2n = rmin(vmin3(e1pp, e1p, e1n), hminLR(e1p));
    R4 d2  = hmax3w(vmax3(e2pp, e2p, e2n));            // @ g-3
    skupd2(skD1, relusub(e1pp, d2));

    R4 e3n = rmin(vmin3(e2pp, e2p, e2n), hminLR(e2p));
    R4 d3  = hmax3w(vmax3(e3pp, e3p, e3n));            // @ g-4
    skupd2(skD2, relusub(e2pp, d3));

    R4 e4n = rmin(vmin3(e3pp, e3p, e3n), hminLR(e3p));
    R4 d4  = hmax3w(vmax3(e4pp, e4p, e4n));            // @ g-5
    skupd2(skF, relusub(e3pp, d4));

    pend = skF;                                         // save finished row for batch fin
    i2 = i1; i1 = i0;
    e1pp = e1n; e2pp = e2n; e3pp = e3n; e4pp = e4n;
}

// ---------- GUARD step: bands 0 / NBANDS-1 ----------
__device__ __forceinline__ void step_guard(
    int g,
    const float* __restrict__ img,
    R4& i2, R4& i1, float4& pr1, float4& pr2,
    R4& e1p, R4& e1pp, R4& e2p, R4& e2pp, R4& e3p, R4& e3pp,
    R4& h1p, R4& h1pp, R4& h2p, R4& h2pp, R4& h3p, R4& h3pp,
    R4& h4p, R4& h4pp,
    R4& skB, R4& skD1, R4& skD2, R4& skF, R4& pend)
{
    R4 i0 = ((unsigned)g < (unsigned)HH) ? cvtrow(pr1, pr2) : r4splat(PINF2);
    {   // clamped-address prefetch (value discarded at consume when OOB)
        int gn = g + 4;
        gn = gn < 0 ? 0 : (gn >= HH ? HH - 1 : gn);
        ldraw(img + (size_t)gn * WW, pr1, pr2);
    }

    R4 e1n = rmin(vmin3(i2, i1, i0), hminLR(i1));
    R4 h1n = hmax3w(e1n);
    if ((unsigned)(g - 1) >= (unsigned)HH) { e1n = r4splat(PINF2); h1n = r4splat(NINF2); }
    R4 d1 = vmax3(h1pp, h1p, h1n);
    skB = relusub(i2, d1);

    R4 e2n = rmin(vmin3(e1pp, e1p, e1n), hminLR(e1p));
    R4 h2n = hmax3w(e2n);
    if ((unsigned)(g - 2) >= (unsigned)HH) { e2n = r4splat(PINF2); h2n = r4splat(NINF2); }
    R4 d2 = vmax3(h2pp, h2p, h2n);
    skupd2(skD1, relusub(e1pp, d2));

    R4 e3n = rmin(vmin3(e2pp, e2p, e2n), hminLR(e2p));
    R4 h3n = hmax3w(e3n);
    if ((unsigned)(g - 3) >= (unsigned)HH) { e3n = r4splat(PINF2); h3n = r4splat(NINF2); }
    R4 d3 = vmax3(h3pp, h3p, h3n);
    skupd2(skD2, relusub(e2pp, d3));

    R4 e4n = rmin(vmin3(e3pp, e3p, e3n), hminLR(e3p));
    R4 h4n = hmax3w(e4n);
    if ((unsigned)(g - 4) >= (unsigned)HH) { h4n = r4splat(NINF2); }
    R4 d4 = vmax3(h4pp, h4p, h4n);
    skupd2(skF, relusub(e3pp, d4));

    pend = skF;
    i2 = i1; i1 = i0;
    e1pp = e1n; e2pp = e2n; e3pp = e3n;
    h1pp = h1n; h2pp = h2n; h3pp = h3n; h4pp = h4n;
}

// ---------- batch point: 4 finreds vs oth loaded LAST batch; issue next 4 ----------
__device__ __forceinline__ void batch_fin(
    int yb, int y0, int y1,
    const float* __restrict__ oth,
    const R4& pend0, const R4& pend1, const R4& pend2, const R4& pend3,
    float4& o0a, float4& o0b, float4& o1a, float4& o1b,
    float4& o2a, float4& o2b, float4& o3a, float4& o3b,
    float& sa, float& sb)
{
    // rows yb..yb+3 finished this group (yb+U < y1 always holds in main loop)
    if (yb + 0 >= y0) finred(pend0, o0a, o0b, sa, sb);
    if (yb + 1 >= y0) finred(pend1, o1a, o1b, sa, sb);
    if (yb + 2 >= y0) finred(pend2, o2a, o2b, sa, sb);
    if (yb + 3 >= y0) finred(pend3, o3a, o3b, sa, sb);
    // issue next group's oth rows (clamped into band); 4-step cover
    int r0 = yb + 4; r0 = r0 < y0 ? y0 : (r0 > y1 - 1 ? y1 - 1 : r0);
    int r1 = yb + 5; r1 = r1 < y0 ? y0 : (r1 > y1 - 1 ? y1 - 1 : r1);
    int r2 = yb + 6; r2 = r2 < y0 ? y0 : (r2 > y1 - 1 ? y1 - 1 : r2);
    int r3 = yb + 7; r3 = r3 < y0 ? y0 : (r3 > y1 - 1 ? y1 - 1 : r3);
    ldraw(oth + (size_t)r0 * WW, o0a, o0b);
    ldraw(oth + (size_t)r1 * WW, o1a, o1b);
    ldraw(oth + (size_t)r2 * WW, o2a, o2b);
    ldraw(oth + (size_t)r3 * WW, o3a, o3b);
}

__global__ __launch_bounds__(256, 2)
void cldice_stream_k(const float* __restrict__ y_pred,
                     const float* __restrict__ y_true,
                     float2* __restrict__ partials, int B)
{
    const int lane = threadIdx.x & 63;
    const int wid  = threadIdx.x >> 6;
    const int wave = blockIdx.x * 4 + wid;
    const int nPerChain = B * NBANDS;
    if (wave >= 2 * nPerChain) return;
    const int chain = wave / nPerChain;
    const int rem   = wave - chain * nPerChain;
    const int im    = rem >> 5;                 // NBANDS == 32
    const int band  = rem & (NBANDS - 1);
    const int y0 = band * BAND;
    const int y1 = y0 + BAND;

    const float* __restrict__ img = (chain ? y_true : y_pred) + (size_t)im * NPIX + lane * 8;
    const float* __restrict__ oth = (chain ? y_pred : y_true) + (size_t)im * NPIX + lane * 8;

    R4 sk0 = r4splat(0u), sk1 = sk0, sk2 = sk0, sk3 = sk0;
    R4 pend0 = sk0, pend1 = sk0, pend2 = sk0, pend3 = sk0;
    float sa = 0.f, sb = 0.f;
    const int g0 = y0 - 5;

    // img staging: 4 pairs, period-4 rotation (matches the 4-unroll)
    float4 pA1, pA2, pB1, pB2, pC1, pC2, pD1, pD2;
    {
        int r0 = g0 + 0; r0 = r0 < 0 ? 0 : r0;
        int r1 = g0 + 1; r1 = r1 < 0 ? 0 : r1;
        int r2 = g0 + 2; r2 = r2 < 0 ? 0 : r2;
        int r3 = g0 + 3; r3 = r3 < 0 ? 0 : r3;
        ldraw(img + (size_t)r0 * WW, pA1, pA2);
        ldraw(img + (size_t)r1 * WW, pB1, pB2);
        ldraw(img + (size_t)r2 * WW, pC1, pC2);
        ldraw(img + (size_t)r3 * WW, pD1, pD2);
    }
    // oth buffers: prologue fill (row y0; first two batches have no fins)
    float4 o0a, o0b, o1a, o1b, o2a, o2b, o3a, o3b;
    ldraw(oth + (size_t)y0 * WW, o0a, o0b);
    ldraw(oth + (size_t)y0 * WW, o1a, o1b);
    ldraw(oth + (size_t)y0 * WW, o2a, o2b);
    ldraw(oth + (size_t)y0 * WW, o3a, o3b);

    if (band == 0 || band == NBANDS - 1) {
        // -------- guarded path (image top/bottom) --------
        R4 i2 = r4splat(PINF2), i1 = i2;
        R4 e1A = i2, e1B = i2, e2A = i2, e2B = i2, e3A = i2, e3B = i2;
        R4 h1A = r4splat(NINF2), h1B = h1A, h2A = h1A, h2B = h1A;
        R4 h3A = h1A, h3B = h1A, h4A = h1A, h4B = h1A;

#define STEPG(U, E1P,E1PP, E2P,E2PP, E3P,E3PP, H1P,H1PP, H2P,H2PP, H3P,H3PP, H4P,H4PP, SKB,SKD1,SKD2,SKF, PR1,PR2, PEND) \
        step_guard(g0 + sbase + U, img, i2, i1, PR1, PR2, \
                   E1P,E1PP, E2P,E2PP, E3P,E3PP, H1P,H1PP, H2P,H2PP, H3P,H3PP, H4P,H4PP, \
                   SKB,SKD1,SKD2,SKF, PEND)
        for (int sbase = 0; sbase < 24; sbase += 4) {
            STEPG(0, e1A,e1B, e2A,e2B, e3A,e3B, h1A,h1B, h2A,h2B, h3A,h3B, h4A,h4B, sk1,sk0,sk3,sk2, pA1,pA2, pend0);
            STEPG(1, e1B,e1A, e2B,e2A, e3B,e3A, h1B,h1A, h2B,h2A, h3B,h3A, h4B,h4A, sk2,sk1,sk0,sk3, pB1,pB2, pend1);
            STEPG(2, e1A,e1B, e2A,e2B, e3A,e3B, h1A,h1B, h2A,h2B, h3A,h3B, h4A,h4B, sk3,sk2,sk1,sk0, pC1,pC2, pend2);
            STEPG(3, e1B,e1A, e2B,e2A, e3B,e3A, h1B,h1A, h2B,h2A, h3B,h3A, h4B,h4A, sk0,sk3,sk2,sk1, pD1,pD2, pend3);
            batch_fin(y0 + sbase - 10, y0, y1, oth, pend0, pend1, pend2, pend3,
                      o0a,o0b, o1a,o1b, o2a,o2b, o3a,o3b, sa, sb);
        }
        {   // tail: steps 24, 25 (rows y0+14, y0+15)
            const int sbase = 24;
            STEPG(0, e1A,e1B, e2A,e2B, e3A,e3B, h1A,h1B, h2A,h2B, h3A,h3B, h4A,h4B, sk1,sk0,sk3,sk2, pA1,pA2, pend0);
            STEPG(1, e1B,e1A, e2B,e2A, e3B,e3A, h1B,h1A, h2B,h2A, h3B,h3A, h4B,h4A, sk2,sk1,sk0,sk3, pB1,pB2, pend1);
            finred(pend0, o0a, o0b, sa, sb);   // oth rows y0+14, y0+15 loaded at batch 20
            finred(pend1, o1a, o1b, sa, sb);
        }
#undef STEPG
    } else {
        // -------- fast path (interior bands; all touched rows real) --------
        R4 i2 = r4splat(PINF2), i1 = i2;
        R4 e1A = i2, e1B = i2, e2A = i2, e2B = i2;
        R4 e3A = i2, e3B = i2, e4A = i2, e4B = i2;

#define STEPF(U, E1P,E1PP, E2P,E2PP, E3P,E3PP, E4P,E4PP, SKB,SKD1,SKD2,SKF, PR1,PR2, PEND) \
        step_fast(g0 + sbase + U, img, i2, i1, PR1, PR2, \
                  E1P,E1PP, E2P,E2PP, E3P,E3PP, E4P,E4PP, SKB,SKD1,SKD2,SKF, PEND)
        for (int sbase = 0; sbase < 24; sbase += 4) {
            STEPF(0, e1A,e1B, e2A,e2B, e3A,e3B, e4A,e4B, sk1,sk0,sk3,sk2, pA1,pA2, pend0);
            STEPF(1, e1B,e1A, e2B,e2A, e3B,e3A, e4B,e4A, sk2,sk1,sk0,sk3, pB1,pB2, pend1);
            STEPF(2, e1A,e1B, e2A,e2B, e3A,e3B, e4A,e4B, sk3,sk2,sk1,sk0, pC1,pC2, pend2);
            STEPF(3, e1B,e1A, e2B,e2A, e3B,e3A, e4B,e4A, sk0,sk3,sk2,sk1, pD1,pD2, pend3);
            batch_fin(y0 + sbase - 10, y0, y1, oth, pend0, pend1, pend2, pend3,
                      o0a,o0b, o1a,o1b, o2a,o2b, o3a,o3b, sa, sb);
        }
        {   // tail: steps 24, 25 (rows y0+14, y0+15)
            const int sbase = 24;
            STEPF(0, e1A,e1B, e2A,e2B, e3A,e3B, e4A,e4B, sk1,sk0,sk3,sk2, pA1,pA2, pend0);
            STEPF(1, e1B,e1A, e2B,e2A, e3B,e3A, e4B,e4A, sk2,sk1,sk0,sk3, pB1,pB2, pend1);
            finred(pend0, o0a, o0b, sa, sb);
            finred(pend1, o1a, o1b, sa, sb);
        }
#undef STEPF
    }

#pragma unroll
    for (int off = 32; off; off >>= 1) {
        sa += __shfl_down(sa, off);
        sb += __shfl_down(sb, off);
    }
    if (lane == 0) partials[wave] = make_float2(sb, sa);   // (.x = sum skel*other, .y = sum skel)
}

__global__ void cldice_final_k(const float2* __restrict__ partials, int nW,
                               float* __restrict__ out)
{
    double s0 = 0, s1 = 0, s2 = 0, s3 = 0;
    for (int i = threadIdx.x; i < nW; i += 256) {
        float2 p = partials[i];        s0 += p.x; s1 += p.y;   // chain 0: skel_pred
        float2 q = partials[nW + i];   s2 += q.x; s3 += q.y;   // chain 1: skel_true
    }
#pragma unroll
    for (int off = 32; off; off >>= 1) {
        s0 += __shfl_down(s0, off);
        s1 += __shfl_down(s1, off);
        s2 += __shfl_down(s2, off);
        s3 += __shfl_down(s3, off);
    }
    __shared__ double sm[4][4];
    int wid = threadIdx.x >> 6, lane = threadIdx.x & 63;
    if (lane == 0) { sm[0][wid] = s0; sm[1][wid] = s1; sm[2][wid] = s2; sm[3][wid] = s3; }
    __syncthreads();
    if (threadIdx.x == 0) {
        double S0 = sm[0][0] + sm[0][1] + sm[0][2] + sm[0][3];
        double S1 = sm[1][0] + sm[1][1] + sm[1][2] + sm[1][3];
        double S2 = sm[2][0] + sm[2][1] + sm[2][2] + sm[2][3];
        double S3 = sm[3][0] + sm[3][1] + sm[3][2] + sm[3][3];
        double tprec = (S0 + 1.0) / (S1 + 1.0);
        double tsens = (S2 + 1.0) / (S3 + 1.0);
        out[0] = (float)(1.0 - 2.0 * (tprec * tsens) / (tprec + tsens));
    }
}

extern "C" void kernel_launch(void* const* d_in, const int* in_sizes, int n_in,
                              void* d_out, int out_size, void* d_ws, size_t ws_size,
                              hipStream_t stream)
{
    const float* y_pred = (const float*)d_in[0];
    const float* y_true = (const float*)d_in[1];
    const int B = in_sizes[0] / NPIX;          // 32 images

    float2* partials = (float2*)d_ws;          // 2*B*NBANDS float2 = 16 KB
    const int nWaves = 2 * B * NBANDS;
    const int blocks = (nWaves + 3) / 4;       // 4 waves per 256-thread block
    cldice_stream_k<<<blocks, 256, 0, stream>>>(y_pred, y_true, partials, B);

    cldice_final_k<<<1, 256, 0, stream>>>(partials, B * NBANDS, (float*)d_out);
}

// Round 20
// 38.350 us; speedup vs baseline: 1.0656x; 1.0656x over previous
//
#include <hip/hip_runtime.h>
#include <hip/hip_fp16.h>

#define HH 512
#define WW 512
#define NPIX (HH*WW)
#define NBANDS 32
#define BAND (HH/NBANDS)     // 16 output rows per wave
#define PINF2 0x7C007C00u    // packed f16 +inf
#define NINF2 0xFC00FC00u    // packed f16 -inf

// ---- packed f16 ops as VOP3P inline asm (proven rounds 8-18) ----
typedef unsigned uh2;
__device__ __forceinline__ uh2 pmin(uh2 a, uh2 b){ uh2 r; asm("v_pk_min_f16 %0, %1, %2" : "=v"(r) : "v"(a), "v"(b)); return r; }
__device__ __forceinline__ uh2 pmax(uh2 a, uh2 b){ uh2 r; asm("v_pk_max_f16 %0, %1, %2" : "=v"(r) : "v"(a), "v"(b)); return r; }
__device__ __forceinline__ uh2 padd(uh2 a, uh2 b){ uh2 r; asm("v_pk_add_f16 %0, %1, %2" : "=v"(r) : "v"(a), "v"(b)); return r; }
__device__ __forceinline__ uh2 psub(uh2 a, uh2 b){ uh2 r; asm("v_pk_add_f16 %0, %1, %2 neg_lo:[0,1] neg_hi:[0,1]" : "=v"(r) : "v"(a), "v"(b)); return r; }
__device__ __forceinline__ uh2 pnfma(uh2 s, uh2 d){ uh2 r; asm("v_pk_fma_f16 %0, %1, %2, %2 neg_lo:[1,0,0] neg_hi:[1,0,0]" : "=v"(r) : "v"(s), "v"(d)); return r; }
__device__ __forceinline__ uh2 pmin3(uh2 a, uh2 b, uh2 c){ return pmin(pmin(a,b),c); }
__device__ __forceinline__ uh2 pmax3(uh2 a, uh2 b, uh2 c){ return pmax(pmax(a,b),c); }
__device__ __forceinline__ uh2 alignh(uh2 lo, uh2 hi){
    uh2 r; asm("v_alignbit_b32 %0, %1, %2, 16" : "=v"(r) : "v"(hi), "v"(lo)); return r;
}
__device__ __forceinline__ uh2 pkrtz(float x, float y){
    uh2 r; asm("v_cvt_pkrtz_f16_f32 %0, %1, %2" : "=v"(r) : "v"(x), "v"(y)); return r;
}
__device__ __forceinline__ float lo_f(uh2 v){ union { uh2 u; __half2 h; } c; c.u = v; return __low2float(c.h); }
__device__ __forceinline__ float hi_f(uh2 v){ union { uh2 u; __half2 h; } c; c.u = v; return __high2float(c.h); }

// ---- DPP full-wave lane shifts ----
__device__ __forceinline__ uh2 dshr1(uh2 v, unsigned old){   // lane i <- lane i-1
    return (uh2)__builtin_amdgcn_update_dpp((int)old, (int)v, 0x138, 0xF, 0xF, false);
}
__device__ __forceinline__ uh2 dshl1(uh2 v, unsigned old){   // lane i <- lane i+1
    return (uh2)__builtin_amdgcn_update_dpp((int)old, (int)v, 0x130, 0xF, 0xF, false);
}

struct R4 { uh2 a, b, c, d; };
__device__ __forceinline__ R4 r4splat(uh2 v){ R4 r; r.a=v; r.b=v; r.c=v; r.d=v; return r; }
__device__ __forceinline__ void ldraw(const float* p, float4& u, float4& v){
    u = *(const float4*)p; v = *(const float4*)(p + 4);
}
__device__ __forceinline__ R4 cvtrow(const float4& u, const float4& v){
    R4 r; r.a = pkrtz(u.x,u.y); r.b = pkrtz(u.z,u.w); r.c = pkrtz(v.x,v.y); r.d = pkrtz(v.z,v.w);
    return r;
}
__device__ __forceinline__ R4 vmin3(const R4& x, const R4& y, const R4& z){
    R4 r; r.a=pmin3(x.a,y.a,z.a); r.b=pmin3(x.b,y.b,z.b); r.c=pmin3(x.c,y.c,z.c); r.d=pmin3(x.d,y.d,z.d); return r;
}
__device__ __forceinline__ R4 vmax3(const R4& x, const R4& y, const R4& z){
    R4 r; r.a=pmax3(x.a,y.a,z.a); r.b=pmax3(x.b,y.b,z.b); r.c=pmax3(x.c,y.c,z.c); r.d=pmax3(x.d,y.d,z.d); return r;
}
__device__ __forceinline__ R4 rmin(const R4& x, const R4& y){
    R4 r; r.a=pmin(x.a,y.a); r.b=pmin(x.b,y.b); r.c=pmin(x.c,y.c); r.d=pmin(x.d,y.d); return r;
}
__device__ __forceinline__ R4 relusub(const R4& p, const R4& d){
    R4 r; r.a=pmax(psub(p.a,d.a),0u); r.b=pmax(psub(p.b,d.b),0u);
          r.c=pmax(psub(p.c,d.c),0u); r.d=pmax(psub(p.d,d.d),0u); return r;
}
// s += d*(1-s)  (relu provably redundant for s,d in [0,1])
__device__ __forceinline__ void skupd2(R4& s, const R4& d){
    s.a = padd(s.a, pnfma(s.a,d.a));
    s.b = padd(s.b, pnfma(s.b,d.b));
    s.c = padd(s.c, pnfma(s.c,d.c));
    s.d = padd(s.d, pnfma(s.d,d.d));
}
__device__ __forceinline__ R4 hminLR(const R4& x){
    uh2 L  = dshr1(x.d, PINF2);
    uh2 Rv = dshl1(x.a, PINF2);
    uh2 s0=alignh(L,x.a), s1=alignh(x.a,x.b), s2=alignh(x.b,x.c), s3=alignh(x.c,x.d), s4=alignh(x.d,Rv);
    R4 m; m.a=pmin(s0,s1); m.b=pmin(s1,s2); m.c=pmin(s2,s3); m.d=pmin(s3,s4); return m;
}
__device__ __forceinline__ R4 hmax3w(const R4& x){
    uh2 L  = dshr1(x.d, NINF2);
    uh2 Rv = dshl1(x.a, NINF2);
    uh2 s0=alignh(L,x.a), s1=alignh(x.a,x.b), s2=alignh(x.b,x.c), s3=alignh(x.c,x.d), s4=alignh(x.d,Rv);
    R4 m; m.a=pmax3(s0,x.a,s1); m.b=pmax3(s1,x.b,s2); m.c=pmax3(s2,x.c,s3); m.d=pmax3(s3,x.d,s4); return m;
}
__device__ __forceinline__ void finred(const R4& skF, const float4& o1, const float4& o2,
                                       float& sa, float& sb){
    float c0=lo_f(skF.a), c1=hi_f(skF.a), c2=lo_f(skF.b), c3=hi_f(skF.b);
    float c4=lo_f(skF.c), c5=hi_f(skF.c), c6=lo_f(skF.d), c7=hi_f(skF.d);
    sa += ((c0+c1)+(c2+c3)) + ((c4+c5)+(c6+c7));
    sb += ((c0*o1.x + c1*o1.y) + (c2*o1.z + c3*o1.w))
        + ((c4*o2.x + c5*o2.y) + (c6*o2.z + c7*o2.w));
}

// ---------- FAST step: interior bands. FIN/LDI/LDO are call-site literals ->
// forceinline folds them: zero dynamic branches, dead loads elided. ----------
__device__ __forceinline__ void step_fast(
    int g, bool FIN, bool LDI, bool LDO,
    const float* __restrict__ img, const float* __restrict__ oth,
    R4& i2, R4& i1, float4& pr1, float4& pr2,
    R4& e1p, R4& e1pp, R4& e2p, R4& e2pp, R4& e3p, R4& e3pp, R4& e4p, R4& e4pp,
    R4& skB, R4& skD1, R4& skD2, R4& skF,
    float4& oc1, float4& oc2, float4& on1, float4& on2,
    float& sa, float& sb)
{
    R4 i0 = cvtrow(pr1, pr2);                          // wait lands here (2-step-old load)
    if (LDI) ldraw(img + (size_t)(g + 2) * WW, pr1, pr2);   // interior: row provably in-image
    if (LDO) {                                          // oth row g-4 (consumed next step)
        on1 = *(const float4*)(oth + (size_t)(g - 4) * WW);
        on2 = *(const float4*)(oth + (size_t)(g - 4) * WW + 4);
    }

    R4 e1n = rmin(vmin3(i2, i1, i0), hminLR(i1));
    R4 d1  = hmax3w(vmax3(e1pp, e1p, e1n));            // dilate(e1) @ g-2
    skB = relusub(i2, d1);

    R4 e2n = rmin(vmin3(e1pp, e1p, e1n), hminLR(e1p));
    R4 d2  = hmax3w(vmax3(e2pp, e2p, e2n));            // @ g-3
    skupd2(skD1, relusub(e1pp, d2));

    R4 e3n = rmin(vmin3(e2pp, e2p, e2n), hminLR(e2p));
    R4 d3  = hmax3w(vmax3(e3pp, e3p, e3n));            // @ g-4
    skupd2(skD2, relusub(e2pp, d3));

    R4 e4n = rmin(vmin3(e3pp, e3p, e3n), hminLR(e3p));
    R4 d4  = hmax3w(vmax3(e4pp, e4p, e4n));            // @ g-5
    skupd2(skF, relusub(e3pp, d4));

    if (FIN) finred(skF, oc1, oc2, sa, sb);

    i2 = i1; i1 = i0;
    e1pp = e1n; e2pp = e2n; e3pp = e3n; e4pp = e4n;    // caller swaps (p,pp)
}

// ---------- GUARD step: bands 0 / NBANDS-1 (R17-proven, unchanged) ----------
__device__ __forceinline__ void step_guard(
    int g, int y0, int y1,
    const float* __restrict__ img, const float* __restrict__ oth,
    R4& i2, R4& i1, float4& pr1, float4& pr2,
    R4& e1p, R4& e1pp, R4& e2p, R4& e2pp, R4& e3p, R4& e3pp,
    R4& h1p, R4& h1pp, R4& h2p, R4& h2pp, R4& h3p, R4& h3pp,
    R4& h4p, R4& h4pp,
    R4& skB, R4& skD1, R4& skD2, R4& skF,
    float4& oc1, float4& oc2, float4& on1, float4& on2,
    float& sa, float& sb)
{
    R4 i0 = ((unsigned)g < (unsigned)HH) ? cvtrow(pr1, pr2) : r4splat(PINF2);
    {   // clamped-address load (value discarded at consume when OOB)
        int gn = g + 2;
        gn = gn < 0 ? 0 : (gn >= HH ? HH - 1 : gn);
        ldraw(img + (size_t)gn * WW, pr1, pr2);
    }
    const int  yf  = g - 5;
    const bool fin = (yf >= y0) && (yf < y1);
    {   // unconditional clamped oth load
        int yfp = yf + 1;
        yfp = yfp < y0 ? y0 : (yfp >= y1 ? y1 - 1 : yfp);
        on1 = *(const float4*)(oth + (size_t)yfp * WW);
        on2 = *(const float4*)(oth + (size_t)yfp * WW + 4);
    }

    R4 e1n = rmin(vmin3(i2, i1, i0), hminLR(i1));
    R4 h1n = hmax3w(e1n);
    if ((unsigned)(g - 1) >= (unsigned)HH) { e1n = r4splat(PINF2); h1n = r4splat(NINF2); }
    R4 d1 = vmax3(h1pp, h1p, h1n);
    skB = relusub(i2, d1);

    R4 e2n = rmin(vmin3(e1pp, e1p, e1n), hminLR(e1p));
    R4 h2n = hmax3w(e2n);
    if ((unsigned)(g - 2) >= (unsigned)HH) { e2n = r4splat(PINF2); h2n = r4splat(NINF2); }
    R4 d2 = vmax3(h2pp, h2p, h2n);
    skupd2(skD1, relusub(e1pp, d2));

    R4 e3n = rmin(vmin3(e2pp, e2p, e2n), hminLR(e2p));
    R4 h3n = hmax3w(e3n);
    if ((unsigned)(g - 3) >= (unsigned)HH) { e3n = r4splat(PINF2); h3n = r4splat(NINF2); }
    R4 d3 = vmax3(h3pp, h3p, h3n);
    skupd2(skD2, relusub(e2pp, d3));

    R4 e4n = rmin(vmin3(e3pp, e3p, e3n), hminLR(e3p));
    R4 h4n = hmax3w(e4n);
    if ((unsigned)(g - 4) >= (unsigned)HH) { h4n = r4splat(NINF2); }
    R4 d4 = vmax3(h4pp, h4p, h4n);
    skupd2(skF, relusub(e3pp, d4));

    if (fin) finred(skF, oc1, oc2, sa, sb);

    i2 = i1; i1 = i0;
    e1pp = e1n; e2pp = e2n; e3pp = e3n;
    h1pp = h1n; h2pp = h2n; h3pp = h3n; h4pp = h4n;
}

__global__ __launch_bounds__(256, 2)
void cldice_stream_k(const float* __restrict__ y_pred,
                     const float* __restrict__ y_true,
                     float2* __restrict__ partials, int B)
{
    const int lane = threadIdx.x & 63;
    const int wid  = threadIdx.x >> 6;
    const int wave = blockIdx.x * 4 + wid;
    const int nPerChain = B * NBANDS;
    if (wave >= 2 * nPerChain) return;
    // L2-locality decode: all bands + both chains of one image dispatch-adjacent
    const int im    = wave >> 6;                // 64 waves per image
    const int chain = (wave >> 5) & 1;
    const int band  = wave & (NBANDS - 1);
    const int y0 = band * BAND;
    const int y1 = y0 + BAND;

    const float* __restrict__ img = (chain ? y_true : y_pred) + (size_t)im * NPIX + lane * 8;
    const float* __restrict__ oth = (chain ? y_pred : y_true) + (size_t)im * NPIX + lane * 8;

    R4 sk0 = r4splat(0u), sk1 = sk0, sk2 = sk0, sk3 = sk0;
    float sa = 0.f, sb = 0.f;
    const int g0 = y0 - 5;
    float4 oA1 = make_float4(0,0,0,0), oA2 = oA1, oB1 = oA1, oB2 = oA1;

    // img staging pairs: pA = even steps, pB = odd steps
    float4 pA1, pA2, pB1, pB2;
    {
        int r0 = g0 < 0 ? 0 : g0;
        int r1 = g0 + 1 < 0 ? 0 : g0 + 1;
        ldraw(img + (size_t)r0 * WW, pA1, pA2);
        ldraw(img + (size_t)r1 * WW, pB1, pB2);
    }

    if (band == 0 || band == NBANDS - 1) {
        // -------- guarded path (image top/bottom), R17-proven --------
        R4 i2 = r4splat(PINF2), i1 = i2;
        R4 e1A = i2, e1B = i2, e2A = i2, e2B = i2, e3A = i2, e3B = i2;
        R4 h1A = r4splat(NINF2), h1B = h1A, h2A = h1A, h2B = h1A;
        R4 h3A = h1A, h3B = h1A, h4A = h1A, h4B = h1A;

#define STEPG(U, E1P,E1PP, E2P,E2PP, E3P,E3PP, H1P,H1PP, H2P,H2PP, H3P,H3PP, H4P,H4PP, SKB,SKD1,SKD2,SKF, PR1,PR2, OC1,OC2,ON1,ON2) \
        step_guard(g0 + sbase + U, y0, y1, img, oth, i2, i1, PR1, PR2, \
                   E1P,E1PP, E2P,E2PP, E3P,E3PP, H1P,H1PP, H2P,H2PP, H3P,H3PP, H4P,H4PP, \
                   SKB,SKD1,SKD2,SKF, OC1,OC2,ON1,ON2, sa, sb)
        for (int sbase = 0; sbase < 24; sbase += 4) {
            STEPG(0, e1A,e1B, e2A,e2B, e3A,e3B, h1A,h1B, h2A,h2B, h3A,h3B, h4A,h4B, sk1,sk0,sk3,sk2, pA1,pA2, oA1,oA2,oB1,oB2);
            STEPG(1, e1B,e1A, e2B,e2A, e3B,e3A, h1B,h1A, h2B,h2A, h3B,h3A, h4B,h4A, sk2,sk1,sk0,sk3, pB1,pB2, oB1,oB2,oA1,oA2);
            STEPG(2, e1A,e1B, e2A,e2B, e3A,e3B, h1A,h1B, h2A,h2B, h3A,h3B, h4A,h4B, sk3,sk2,sk1,sk0, pA1,pA2, oA1,oA2,oB1,oB2);
            STEPG(3, e1B,e1A, e2B,e2A, e3B,e3A, h1B,h1A, h2B,h2A, h3B,h3A, h4B,h4A, sk0,sk3,sk2,sk1, pB1,pB2, oB1,oB2,oA1,oA2);
        }
        {   // tail: steps 24, 25
            const int sbase = 24;
            STEPG(0, e1A,e1B, e2A,e2B, e3A,e3B, h1A,h1B, h2A,h2B, h3A,h3B, h4A,h4B, sk1,sk0,sk3,sk2, pA1,pA2, oA1,oA2,oB1,oB2);
            STEPG(1, e1B,e1A, e2B,e2A, e3B,e3A, h1B,h1A, h2B,h2A, h3B,h3A, h4B,h4A, sk2,sk1,sk0,sk3, pB1,pB2, oB1,oB2,oA1,oA2);
        }
#undef STEPG
    } else {
        // -------- fast path: 26 steps emitted with literal flags --------
        R4 i2 = r4splat(PINF2), i1 = i2;
        R4 e1A = i2, e1B = i2, e2A = i2, e2B = i2;
        R4 e3A = i2, e3B = i2, e4A = i2, e4B = i2;

        // phase macros: S is the absolute step (g = g0 + S); S%4 picks the pattern
#define P0(S, FIN, LDI, LDO) \
        step_fast(g0 + (S), FIN, LDI, LDO, img, oth, i2, i1, pA1, pA2, \
                  e1A,e1B, e2A,e2B, e3A,e3B, e4A,e4B, sk1,sk0,sk3,sk2, \
                  oA1,oA2, oB1,oB2, sa, sb)
#define P1(S, FIN, LDI, LDO) \
        step_fast(g0 + (S), FIN, LDI, LDO, img, oth, i2, i1, pB1, pB2, \
                  e1B,e1A, e2B,e2A, e3B,e3A, e4B,e4A, sk2,sk1,sk0,sk3, \
                  oB1,oB2, oA1,oA2, sa, sb)
#define P2(S, FIN, LDI, LDO) \
        step_fast(g0 + (S), FIN, LDI, LDO, img, oth, i2, i1, pA1, pA2, \
                  e1A,e1B, e2A,e2B, e3A,e3B, e4A,e4B, sk3,sk2,sk1,sk0, \
                  oA1,oA2, oB1,oB2, sa, sb)
#define P3(S, FIN, LDI, LDO) \
        step_fast(g0 + (S), FIN, LDI, LDO, img, oth, i2, i1, pB1, pB2, \
                  e1B,e1A, e2B,e2A, e3B,e3A, e4B,e4A, sk0,sk3,sk2,sk1, \
                  oB1,oB2, oA1,oA2, sa, sb)

        // prologue: s = 0..8, no fin, no oth
        P0(0,  false, true, false);
        P1(1,  false, true, false);
        P2(2,  false, true, false);
        P3(3,  false, true, false);
        P0(4,  false, true, false);
        P1(5,  false, true, false);
        P2(6,  false, true, false);
        P3(7,  false, true, false);
        P0(8,  false, true, false);
        P1(9,  false, true, true );   // loads oth row y0 into oA (consumed s=10)
        // main: s = 10..23, fin + both loads every step
        P2(10, true,  true, true );
        P3(11, true,  true, true );
        P0(12, true,  true, true );
        P1(13, true,  true, true );
        P2(14, true,  true, true );
        P3(15, true,  true, true );
        P0(16, true,  true, true );
        P1(17, true,  true, true );
        P2(18, true,  true, true );
        P3(19, true,  true, true );
        P0(20, true,  true, true );
        P1(21, true,  true, true );
        P2(22, true,  true, true );
        P3(23, true,  true, true );
        // epilogue: img loads elided (consumers beyond s=25); s=25 has no oth load
        P0(24, true,  false, true );  // loads oth row y0+15 into oB (consumed s=25)
        P1(25, true,  false, false);
#undef P0
#undef P1
#undef P2
#undef P3
    }

#pragma unroll
    for (int off = 32; off; off >>= 1) {
        sa += __shfl_down(sa, off);
        sb += __shfl_down(sb, off);
    }
    if (lane == 0) {
        int pidx = chain * nPerChain + im * NBANDS + band;
        partials[pidx] = make_float2(sb, sa);   // (.x = sum skel*other, .y = sum skel)
    }
}

__global__ void cldice_final_k(const float2* __restrict__ partials, int nW,
                               float* __restrict__ out)
{
    double s0 = 0, s1 = 0, s2 = 0, s3 = 0;
    for (int i = threadIdx.x; i < nW; i += 256) {
        float2 p = partials[i];        s0 += p.x; s1 += p.y;   // chain 0: skel_pred
        float2 q = partials[nW + i];   s2 += q.x; s3 += q.y;   // chain 1: skel_true
    }
#pragma unroll
    for (int off = 32; off; off >>= 1) {
        s0 += __shfl_down(s0, off);
        s1 += __shfl_down(s1, off);
        s2 += __shfl_down(s2, off);
        s3 += __shfl_down(s3, off);
    }
    __shared__ double sm[4][4];
    int wid = threadIdx.x >> 6, lane = threadIdx.x & 63;
    if (lane == 0) { sm[0][wid] = s0; sm[1][wid] = s1; sm[2][wid] = s2; sm[3][wid] = s3; }
    __syncthreads();
    if (threadIdx.x == 0) {
        double S0 = sm[0][0] + sm[0][1] + sm[0][2] + sm[0][3];
        double S1 = sm[1][0] + sm[1][1] + sm[1][2] + sm[1][3];
        double S2 = sm[2][0] + sm[2][1] + sm[2][2] + sm[2][3];
        double S3 = sm[3][0] + sm[3][1] + sm[3][2] + sm[3][3];
        double tprec = (S0 + 1.0) / (S1 + 1.0);
        double tsens = (S2 + 1.0) / (S3 + 1.0);
        out[0] = (float)(1.0 - 2.0 * (tprec * tsens) / (tprec + tsens));
    }
}

extern "C" void kernel_launch(void* const* d_in, const int* in_sizes, int n_in,
                              void* d_out, int out_size, void* d_ws, size_t ws_size,
                              hipStream_t stream)
{
    const float* y_pred = (const float*)d_in[0];
    const float* y_true = (const float*)d_in[1];
    const int B = in_sizes[0] / NPIX;          // 32 images

    float2* partials = (float2*)d_ws;          // 2*B*NBANDS float2 = 16 KB
    const int nWaves = 2 * B * NBANDS;
    const int blocks = (nWaves + 3) / 4;       // 4 waves per 256-thread block
    cldice_stream_k<<<blocks, 256, 0, stream>>>(y_pred, y_true, partials, B);

    cldice_final_k<<<1, 256, 0, stream>>>(partials, B * NBANDS, (float*)d_out);
}

// Round 21
// 37.265 us; speedup vs baseline: 1.0966x; 1.0291x over previous
//
#include <hip/hip_runtime.h>
#include <hip/hip_fp16.h>

#define HH 512
#define WW 512
#define NPIX (HH*WW)
#define NBANDS 32
#define BAND (HH/NBANDS)     // 16 output rows per wave
#define PINF2 0x7C007C00u    // packed f16 +inf
#define NINF2 0xFC00FC00u    // packed f16 -inf
#define ONE2  0x3C003C00u    // packed f16 (1.0, 1.0)

// ---- packed f16 ops as VOP3P inline asm (proven rounds 8-20) ----
typedef unsigned uh2;
__device__ __forceinline__ uh2 pmin(uh2 a, uh2 b){ uh2 r; asm("v_pk_min_f16 %0, %1, %2" : "=v"(r) : "v"(a), "v"(b)); return r; }
__device__ __forceinline__ uh2 pmax(uh2 a, uh2 b){ uh2 r; asm("v_pk_max_f16 %0, %1, %2" : "=v"(r) : "v"(a), "v"(b)); return r; }
__device__ __forceinline__ uh2 padd(uh2 a, uh2 b){ uh2 r; asm("v_pk_add_f16 %0, %1, %2" : "=v"(r) : "v"(a), "v"(b)); return r; }
__device__ __forceinline__ uh2 psub(uh2 a, uh2 b){ uh2 r; asm("v_pk_add_f16 %0, %1, %2 neg_lo:[0,1] neg_hi:[0,1]" : "=v"(r) : "v"(a), "v"(b)); return r; }
__device__ __forceinline__ uh2 pnfma(uh2 s, uh2 d){ uh2 r; asm("v_pk_fma_f16 %0, %1, %2, %2 neg_lo:[1,0,0] neg_hi:[1,0,0]" : "=v"(r) : "v"(s), "v"(d)); return r; }
__device__ __forceinline__ uh2 pmin3(uh2 a, uh2 b, uh2 c){ return pmin(pmin(a,b),c); }
__device__ __forceinline__ uh2 pmax3(uh2 a, uh2 b, uh2 c){ return pmax(pmax(a,b),c); }
__device__ __forceinline__ uh2 alignh(uh2 lo, uh2 hi){
    uh2 r; asm("v_alignbit_b32 %0, %1, %2, 16" : "=v"(r) : "v"(hi), "v"(lo)); return r;
}
__device__ __forceinline__ uh2 pkrtz(float x, float y){
    uh2 r; asm("v_cvt_pkrtz_f16_f32 %0, %1, %2" : "=v"(r) : "v"(x), "v"(y)); return r;
}
__device__ __forceinline__ float lo_f(uh2 v){ union { uh2 u; __half2 h; } c; c.u = v; return __low2float(c.h); }
__device__ __forceinline__ float hi_f(uh2 v){ union { uh2 u; __half2 h; } c; c.u = v; return __high2float(c.h); }

// packed f16 dot-2 with f32 accumulate (exact f32 accumulation)
#if defined(__has_builtin)
#if __has_builtin(__builtin_amdgcn_fdot2)
#define HAVE_FDOT2 1
#endif
#endif
#ifdef HAVE_FDOT2
typedef _Float16 hv2 __attribute__((ext_vector_type(2)));
__device__ __forceinline__ float fdot2(uh2 a, uh2 b, float c){
    union { uh2 u; hv2 h; } A, B; A.u = a; B.u = b;
    return __builtin_amdgcn_fdot2(A.h, B.h, c, false);
}
#endif

// ---- DPP full-wave lane shifts ----
__device__ __forceinline__ uh2 dshr1(uh2 v, unsigned old){   // lane i <- lane i-1
    return (uh2)__builtin_amdgcn_update_dpp((int)old, (int)v, 0x138, 0xF, 0xF, false);
}
__device__ __forceinline__ uh2 dshl1(uh2 v, unsigned old){   // lane i <- lane i+1
    return (uh2)__builtin_amdgcn_update_dpp((int)old, (int)v, 0x130, 0xF, 0xF, false);
}

struct R4 { uh2 a, b, c, d; };
__device__ __forceinline__ R4 r4splat(uh2 v){ R4 r; r.a=v; r.b=v; r.c=v; r.d=v; return r; }
__device__ __forceinline__ void ldraw(const float* p, float4& u, float4& v){
    u = *(const float4*)p; v = *(const float4*)(p + 4);
}
__device__ __forceinline__ R4 cvtrow(const float4& u, const float4& v){
    R4 r; r.a = pkrtz(u.x,u.y); r.b = pkrtz(u.z,u.w); r.c = pkrtz(v.x,v.y); r.d = pkrtz(v.z,v.w);
    return r;
}
__device__ __forceinline__ R4 vmin3(const R4& x, const R4& y, const R4& z){
    R4 r; r.a=pmin3(x.a,y.a,z.a); r.b=pmin3(x.b,y.b,z.b); r.c=pmin3(x.c,y.c,z.c); r.d=pmin3(x.d,y.d,z.d); return r;
}
__device__ __forceinline__ R4 vmax3(const R4& x, const R4& y, const R4& z){
    R4 r; r.a=pmax3(x.a,y.a,z.a); r.b=pmax3(x.b,y.b,z.b); r.c=pmax3(x.c,y.c,z.c); r.d=pmax3(x.d,y.d,z.d); return r;
}
__device__ __forceinline__ R4 rmin(const R4& x, const R4& y){
    R4 r; r.a=pmin(x.a,y.a); r.b=pmin(x.b,y.b); r.c=pmin(x.c,y.c); r.d=pmin(x.d,y.d); return r;
}
__device__ __forceinline__ R4 relusub(const R4& p, const R4& d){
    R4 r; r.a=pmax(psub(p.a,d.a),0u); r.b=pmax(psub(p.b,d.b),0u);
          r.c=pmax(psub(p.c,d.c),0u); r.d=pmax(psub(p.d,d.d),0u); return r;
}
// s += d*(1-s)  (relu provably redundant for s,d in [0,1])
__device__ __forceinline__ void skupd2(R4& s, const R4& d){
    s.a = padd(s.a, pnfma(s.a,d.a));
    s.b = padd(s.b, pnfma(s.b,d.b));
    s.c = padd(s.c, pnfma(s.c,d.c));
    s.d = padd(s.d, pnfma(s.d,d.d));
}
__device__ __forceinline__ R4 hminLR(const R4& x){
    uh2 L  = dshr1(x.d, PINF2);
    uh2 Rv = dshl1(x.a, PINF2);
    uh2 s0=alignh(L,x.a), s1=alignh(x.a,x.b), s2=alignh(x.b,x.c), s3=alignh(x.c,x.d), s4=alignh(x.d,Rv);
    R4 m; m.a=pmin(s0,s1); m.b=pmin(s1,s2); m.c=pmin(s2,s3); m.d=pmin(s3,s4); return m;
}
__device__ __forceinline__ R4 hmax3w(const R4& x){
    uh2 L  = dshr1(x.d, NINF2);
    uh2 Rv = dshl1(x.a, NINF2);
    uh2 s0=alignh(L,x.a), s1=alignh(x.a,x.b), s2=alignh(x.b,x.c), s3=alignh(x.c,x.d), s4=alignh(x.d,Rv);
    R4 m; m.a=pmax3(s0,x.a,s1); m.b=pmax3(s1,x.b,s2); m.c=pmax3(s2,x.c,s3); m.d=pmax3(s3,x.d,s4); return m;
}

// fin reduction: dot2 path (12 inst) with exact f32 accumulation; fallback = R20 path
__device__ __forceinline__ void finred(const R4& skF, const float4& o1, const float4& o2,
                                       float& sa0, float& sa1, float& sb0, float& sb1){
#ifdef HAVE_FDOT2
    uh2 oa = pkrtz(o1.x, o1.y), ob = pkrtz(o1.z, o1.w);
    uh2 oc = pkrtz(o2.x, o2.y), od = pkrtz(o2.z, o2.w);
    sa0 = fdot2(skF.a, ONE2, sa0); sa1 = fdot2(skF.c, ONE2, sa1);
    sa0 = fdot2(skF.b, ONE2, sa0); sa1 = fdot2(skF.d, ONE2, sa1);
    sb0 = fdot2(skF.a, oa, sb0);   sb1 = fdot2(skF.c, oc, sb1);
    sb0 = fdot2(skF.b, ob, sb0);   sb1 = fdot2(skF.d, od, sb1);
#else
    float c0=lo_f(skF.a), c1=hi_f(skF.a), c2=lo_f(skF.b), c3=hi_f(skF.b);
    float c4=lo_f(skF.c), c5=hi_f(skF.c), c6=lo_f(skF.d), c7=hi_f(skF.d);
    sa0 += (c0+c1)+(c2+c3);
    sa1 += (c4+c5)+(c6+c7);
    sb0 += (c0*o1.x + c1*o1.y) + (c2*o1.z + c3*o1.w);
    sb1 += (c4*o2.x + c5*o2.y) + (c6*o2.z + c7*o2.w);
#endif
}

// ---------- FAST step: interior bands. FIN/LDI/LDO are call-site literals ----------
__device__ __forceinline__ void step_fast(
    int g, bool FIN, bool LDI, bool LDO,
    const float* __restrict__ img, const float* __restrict__ oth,
    R4& i2, R4& i1, float4& pr1, float4& pr2,
    R4& e1p, R4& e1pp, R4& e2p, R4& e2pp, R4& e3p, R4& e3pp, R4& e4p, R4& e4pp,
    R4& skB, R4& skD1, R4& skD2, R4& skF,
    float4& oc1, float4& oc2, float4& on1, float4& on2,
    float& sa0, float& sa1, float& sb0, float& sb1)
{
    R4 i0 = cvtrow(pr1, pr2);                          // wait lands here (2-step-old load)
    if (LDI) ldraw(img + (size_t)(g + 2) * WW, pr1, pr2);
    if (LDO) {                                          // oth row g-4 (consumed next step)
        on1 = *(const float4*)(oth + (size_t)(g - 4) * WW);
        on2 = *(const float4*)(oth + (size_t)(g - 4) * WW + 4);
    }

    R4 e1n = rmin(vmin3(i2, i1, i0), hminLR(i1));
    R4 d1  = hmax3w(vmax3(e1pp, e1p, e1n));            // dilate(e1) @ g-2
    skB = relusub(i2, d1);

    R4 e2n = rmin(vmin3(e1pp, e1p, e1n), hminLR(e1p));
    R4 d2  = hmax3w(vmax3(e2pp, e2p, e2n));            // @ g-3
    skupd2(skD1, relusub(e1pp, d2));

    R4 e3n = rmin(vmin3(e2pp, e2p, e2n), hminLR(e2p));
    R4 d3  = hmax3w(vmax3(e3pp, e3p, e3n));            // @ g-4
    skupd2(skD2, relusub(e2pp, d3));

    R4 e4n = rmin(vmin3(e3pp, e3p, e3n), hminLR(e3p));
    R4 d4  = hmax3w(vmax3(e4pp, e4p, e4n));            // @ g-5
    skupd2(skF, relusub(e3pp, d4));

    if (FIN) finred(skF, oc1, oc2, sa0, sa1, sb0, sb1);

    i2 = i1; i1 = i0;
    e1pp = e1n; e2pp = e2n; e3pp = e3n; e4pp = e4n;
}

// ---------- GUARD step: bands 0 / NBANDS-1 ----------
__device__ __forceinline__ void step_guard(
    int g, int y0, int y1,
    const float* __restrict__ img, const float* __restrict__ oth,
    R4& i2, R4& i1, float4& pr1, float4& pr2,
    R4& e1p, R4& e1pp, R4& e2p, R4& e2pp, R4& e3p, R4& e3pp,
    R4& h1p, R4& h1pp, R4& h2p, R4& h2pp, R4& h3p, R4& h3pp,
    R4& h4p, R4& h4pp,
    R4& skB, R4& skD1, R4& skD2, R4& skF,
    float4& oc1, float4& oc2, float4& on1, float4& on2,
    float& sa0, float& sa1, float& sb0, float& sb1)
{
    R4 i0 = ((unsigned)g < (unsigned)HH) ? cvtrow(pr1, pr2) : r4splat(PINF2);
    {
        int gn = g + 2;
        gn = gn < 0 ? 0 : (gn >= HH ? HH - 1 : gn);
        ldraw(img + (size_t)gn * WW, pr1, pr2);
    }
    const int  yf  = g - 5;
    const bool fin = (yf >= y0) && (yf < y1);
    {
        int yfp = yf + 1;
        yfp = yfp < y0 ? y0 : (yfp >= y1 ? y1 - 1 : yfp);
        on1 = *(const float4*)(oth + (size_t)yfp * WW);
        on2 = *(const float4*)(oth + (size_t)yfp * WW + 4);
    }

    R4 e1n = rmin(vmin3(i2, i1, i0), hminLR(i1));
    R4 h1n = hmax3w(e1n);
    if ((unsigned)(g - 1) >= (unsigned)HH) { e1n = r4splat(PINF2); h1n = r4splat(NINF2); }
    R4 d1 = vmax3(h1pp, h1p, h1n);
    skB = relusub(i2, d1);

    R4 e2n = rmin(vmin3(e1pp, e1p, e1n), hminLR(e1p));
    R4 h2n = hmax3w(e2n);
    if ((unsigned)(g - 2) >= (unsigned)HH) { e2n = r4splat(PINF2); h2n = r4splat(NINF2); }
    R4 d2 = vmax3(h2pp, h2p, h2n);
    skupd2(skD1, relusub(e1pp, d2));

    R4 e3n = rmin(vmin3(e2pp, e2p, e2n), hminLR(e2p));
    R4 h3n = hmax3w(e3n);
    if ((unsigned)(g - 3) >= (unsigned)HH) { e3n = r4splat(PINF2); h3n = r4splat(NINF2); }
    R4 d3 = vmax3(h3pp, h3p, h3n);
    skupd2(skD2, relusub(e2pp, d3));

    R4 e4n = rmin(vmin3(e3pp, e3p, e3n), hminLR(e3p));
    R4 h4n = hmax3w(e4n);
    if ((unsigned)(g - 4) >= (unsigned)HH) { h4n = r4splat(NINF2); }
    R4 d4 = vmax3(h4pp, h4p, h4n);
    skupd2(skF, relusub(e3pp, d4));

    if (fin) finred(skF, oc1, oc2, sa0, sa1, sb0, sb1);

    i2 = i1; i1 = i0;
    e1pp = e1n; e2pp = e2n; e3pp = e3n;
    h1pp = h1n; h2pp = h2n; h3pp = h3n; h4pp = h4n;
}

__global__ __launch_bounds__(256, 2)
void cldice_stream_k(const float* __restrict__ y_pred,
                     const float* __restrict__ y_true,
                     float2* __restrict__ partials, int B)
{
    const int lane = threadIdx.x & 63;
    const int wid  = threadIdx.x >> 6;
    const int wave = blockIdx.x * 4 + wid;
    const int nPerChain = B * NBANDS;
    if (wave >= 2 * nPerChain) return;
    const int im    = wave >> 6;                // 64 waves per image (L2 locality)
    const int chain = (wave >> 5) & 1;
    const int band  = wave & (NBANDS - 1);
    const int y0 = band * BAND;
    const int y1 = y0 + BAND;

    const float* __restrict__ img = (chain ? y_true : y_pred) + (size_t)im * NPIX + lane * 8;
    const float* __restrict__ oth = (chain ? y_pred : y_true) + (size_t)im * NPIX + lane * 8;

    R4 sk0 = r4splat(0u), sk1 = sk0, sk2 = sk0, sk3 = sk0;
    float sa0 = 0.f, sa1 = 0.f, sb0 = 0.f, sb1 = 0.f;
    const int g0 = y0 - 5;
    float4 oA1 = make_float4(0,0,0,0), oA2 = oA1, oB1 = oA1, oB2 = oA1;

    float4 pA1, pA2, pB1, pB2;
    {
        int r0 = g0 < 0 ? 0 : g0;
        int r1 = g0 + 1 < 0 ? 0 : g0 + 1;
        ldraw(img + (size_t)r0 * WW, pA1, pA2);
        ldraw(img + (size_t)r1 * WW, pB1, pB2);
    }

    if (band == 0 || band == NBANDS - 1) {
        // -------- guarded path (image top/bottom) --------
        R4 i2 = r4splat(PINF2), i1 = i2;
        R4 e1A = i2, e1B = i2, e2A = i2, e2B = i2, e3A = i2, e3B = i2;
        R4 h1A = r4splat(NINF2), h1B = h1A, h2A = h1A, h2B = h1A;
        R4 h3A = h1A, h3B = h1A, h4A = h1A, h4B = h1A;

#define STEPG(U, E1P,E1PP, E2P,E2PP, E3P,E3PP, H1P,H1PP, H2P,H2PP, H3P,H3PP, H4P,H4PP, SKB,SKD1,SKD2,SKF, PR1,PR2, OC1,OC2,ON1,ON2) \
        step_guard(g0 + sbase + U, y0, y1, img, oth, i2, i1, PR1, PR2, \
                   E1P,E1PP, E2P,E2PP, E3P,E3PP, H1P,H1PP, H2P,H2PP, H3P,H3PP, H4P,H4PP, \
                   SKB,SKD1,SKD2,SKF, OC1,OC2,ON1,ON2, sa0, sa1, sb0, sb1)
        for (int sbase = 0; sbase < 24; sbase += 4) {
            STEPG(0, e1A,e1B, e2A,e2B, e3A,e3B, h1A,h1B, h2A,h2B, h3A,h3B, h4A,h4B, sk1,sk0,sk3,sk2, pA1,pA2, oA1,oA2,oB1,oB2);
            STEPG(1, e1B,e1A, e2B,e2A, e3B,e3A, h1B,h1A, h2B,h2A, h3B,h3A, h4B,h4A, sk2,sk1,sk0,sk3, pB1,pB2, oB1,oB2,oA1,oA2);
            STEPG(2, e1A,e1B, e2A,e2B, e3A,e3B, h1A,h1B, h2A,h2B, h3A,h3B, h4A,h4B, sk3,sk2,sk1,sk0, pA1,pA2, oA1,oA2,oB1,oB2);
            STEPG(3, e1B,e1A, e2B,e2A, e3B,e3A, h1B,h1A, h2B,h2A, h3B,h3A, h4B,h4A, sk0,sk3,sk2,sk1, pB1,pB2, oB1,oB2,oA1,oA2);
        }
        {
            const int sbase = 24;
            STEPG(0, e1A,e1B, e2A,e2B, e3A,e3B, h1A,h1B, h2A,h2B, h3A,h3B, h4A,h4B, sk1,sk0,sk3,sk2, pA1,pA2, oA1,oA2,oB1,oB2);
            STEPG(1, e1B,e1A, e2B,e2A, e3B,e3A, h1B,h1A, h2B,h2A, h3B,h3A, h4B,h4A, sk2,sk1,sk0,sk3, pB1,pB2, oB1,oB2,oA1,oA2);
        }
#undef STEPG
    } else {
        // -------- fast path: 26 steps, literal flags --------
        R4 i2 = r4splat(PINF2), i1 = i2;
        R4 e1A = i2, e1B = i2, e2A = i2, e2B = i2;
        R4 e3A = i2, e3B = i2, e4A = i2, e4B = i2;

#define P0(S, FIN, LDI, LDO) \
        step_fast(g0 + (S), FIN, LDI, LDO, img, oth, i2, i1, pA1, pA2, \
                  e1A,e1B, e2A,e2B, e3A,e3B, e4A,e4B, sk1,sk0,sk3,sk2, \
                  oA1,oA2, oB1,oB2, sa0, sa1, sb0, sb1)
#define P1(S, FIN, LDI, LDO) \
        step_fast(g0 + (S), FIN, LDI, LDO, img, oth, i2, i1, pB1, pB2, \
                  e1B,e1A, e2B,e2A, e3B,e3A, e4B,e4A, sk2,sk1,sk0,sk3, \
                  oB1,oB2, oA1,oA2, sa0, sa1, sb0, sb1)
#define P2(S, FIN, LDI, LDO) \
        step_fast(g0 + (S), FIN, LDI, LDO, img, oth, i2, i1, pA1, pA2, \
                  e1A,e1B, e2A,e2B, e3A,e3B, e4A,e4B, sk3,sk2,sk1,sk0, \
                  oA1,oA2, oB1,oB2, sa0, sa1, sb0, sb1)
#define P3(S, FIN, LDI, LDO) \
        step_fast(g0 + (S), FIN, LDI, LDO, img, oth, i2, i1, pB1, pB2, \
                  e1B,e1A, e2B,e2A, e3B,e3A, e4B,e4A, sk0,sk3,sk2,sk1, \
                  oB1,oB2, oA1,oA2, sa0, sa1, sb0, sb1)

        P0(0,  false, true, false);
        P1(1,  false, true, false);
        P2(2,  false, true, false);
        P3(3,  false, true, false);
        P0(4,  false, true, false);
        P1(5,  false, true, false);
        P2(6,  false, true, false);
        P3(7,  false, true, false);
        P0(8,  false, true, false);
        P1(9,  false, true, true );   // loads oth row y0 (consumed s=10)
        P2(10, true,  true, true );
        P3(11, true,  true, true );
        P0(12, true,  true, true );
        P1(13, true,  true, true );
        P2(14, true,  true, true );
        P3(15, true,  true, true );
        P0(16, true,  true, true );
        P1(17, true,  true, true );
        P2(18, true,  true, true );
        P3(19, true,  true, true );
        P0(20, true,  true, true );
        P1(21, true,  true, true );
        P2(22, true,  true, true );
        P3(23, true,  true, true );
        P0(24, true,  false, true );  // loads oth row y0+15 (consumed s=25)
        P1(25, true,  false, false);
#undef P0
#undef P1
#undef P2
#undef P3
    }

    float sa = sa0 + sa1, sb = sb0 + sb1;
#pragma unroll
    for (int off = 32; off; off >>= 1) {
        sa += __shfl_down(sa, off);
        sb += __shfl_down(sb, off);
    }
    if (lane == 0) {
        int pidx = chain * nPerChain + im * NBANDS + band;
        partials[pidx] = make_float2(sb, sa);   // (.x = sum skel*other, .y = sum skel)
    }
}

__global__ void cldice_final_k(const float2* __restrict__ partials, int nW,
                               float* __restrict__ out)
{
    double s0 = 0, s1 = 0, s2 = 0, s3 = 0;
    for (int i = threadIdx.x; i < nW; i += 256) {
        float2 p = partials[i];        s0 += p.x; s1 += p.y;   // chain 0: skel_pred
        float2 q = partials[nW + i];   s2 += q.x; s3 += q.y;   // chain 1: skel_true
    }
#pragma unroll
    for (int off = 32; off; off >>= 1) {
        s0 += __shfl_down(s0, off);
        s1 += __shfl_down(s1, off);
        s2 += __shfl_down(s2, off);
        s3 += __shfl_down(s3, off);
    }
    __shared__ double sm[4][4];
    int wid = threadIdx.x >> 6, lane = threadIdx.x & 63;
    if (lane == 0) { sm[0][wid] = s0; sm[1][wid] = s1; sm[2][wid] = s2; sm[3][wid] = s3; }
    __syncthreads();
    if (threadIdx.x == 0) {
        double S0 = sm[0][0] + sm[0][1] + sm[0][2] + sm[0][3];
        double S1 = sm[1][0] + sm[1][1] + sm[1][2] + sm[1][3];
        double S2 = sm[2][0] + sm[2][1] + sm[2][2] + sm[2][3];
        double S3 = sm[3][0] + sm[3][1] + sm[3][2] + sm[3][3];
        double tprec = (S0 + 1.0) / (S1 + 1.0);
        double tsens = (S2 + 1.0) / (S3 + 1.0);
        out[0] = (float)(1.0 - 2.0 * (tprec * tsens) / (tprec + tsens));
    }
}

extern "C" void kernel_launch(void* const* d_in, const int* in_sizes, int n_in,
                              void* d_out, int out_size, void* d_ws, size_t ws_size,
                              hipStream_t stream)
{
    const float* y_pred = (const float*)d_in[0];
    const float* y_true = (const float*)d_in[1];
    const int B = in_sizes[0] / NPIX;          // 32 images

    float2* partials = (float2*)d_ws;          // 2*B*NBANDS float2 = 16 KB
    const int nWaves = 2 * B * NBANDS;
    const int blocks = (nWaves + 3) / 4;       // 4 waves per 256-thread block
    cldice_stream_k<<<blocks, 256, 0, stream>>>(y_pred, y_true, partials, B);

    cldice_final_k<<<1, 256, 0, stream>>>(partials, B * NBANDS, (float*)d_out);
}